// Round 18
// baseline (827.052 us; speedup 1.0000x reference)
//
#include <hip/hip_runtime.h>
#include <hip/hip_bf16.h>
#include <hip/hip_fp8.h>
#include <hip/hip_cooperative_groups.h>
#include <cstdint>

namespace cg = cooperative_groups;

static constexpr int B_  = 8;
static constexpr int C_  = 64;
static constexpr int N_  = 65536;
static constexpr int Rr  = 32;
static constexpr int R3  = Rr * Rr * Rr;        // 32768 = 2^15
static constexpr int PBLK  = 16;
static constexpr int PBLKM = 64;
static constexpr int PTS_PER_BLK  = N_ / PBLK;  // 4096
static constexpr int PTS_PER_BLKM = N_ / PBLKM; // 1024

typedef float f32x4 __attribute__((ext_vector_type(4)));

__device__ __forceinline__ unsigned int pack4_fp8(float a, float b, float c, float d) {
    __hip_fp8x4_e4m3 q(make_float4(a, b, c, d));
    return *reinterpret_cast<unsigned int*>(&q);
}
__device__ __forceinline__ float4 unpack4_fp8(unsigned int u) {
    __hip_fp8x4_e4m3 q;
    *reinterpret_cast<unsigned int*>(&q) = u;
    return (float4)q;
}

// ================= cooperative MEGA kernel: 7 phases, 6 grid.sync =================
__global__ __launch_bounds__(256, 4) void mega_kernel(
    const float* __restrict__ features, const float* __restrict__ coords,
    float* __restrict__ nc_out, float* __restrict__ out,
    float* __restrict__ acc, int* __restrict__ counts, int* __restrict__ cursor,
    int* __restrict__ flat, int4* __restrict__ clist, int* __restrict__ n_occ,
    float* __restrict__ pmean, float* __restrict__ pmax,
    unsigned char* __restrict__ ftS)
{
    cg::grid_group grid = cg::this_grid();
    const int bid  = blockIdx.x;     // 0..1023
    const int t    = threadIdx.x;    // 0..255
    const int lane = t & 63, wv = t >> 6;
    __shared__ __align__(16) char shraw[17408];

    // ---- phase A: pmean partials (blocks 0..383) + zero counts (384..639) ----
    if (bid < B_ * 3 * PBLK) {
        const int blk = bid & (PBLK - 1), ba = bid / PBLK;
        const float4* p = (const float4*)(coords + (size_t)ba * N_ + (size_t)blk * PTS_PER_BLK);
        float s = 0.f;
        #pragma unroll
        for (int k = 0; k < 4; ++k) { float4 v = p[k * 256 + t]; s += (v.x + v.y) + (v.z + v.w); }
        #pragma unroll
        for (int off = 32; off >= 1; off >>= 1) s += __shfl_down(s, off, 64);
        float* sm = (float*)shraw;
        if (lane == 0) sm[wv] = s;
        __syncthreads();
        if (t == 0) pmean[bid] = sm[0] + sm[1] + sm[2] + sm[3];
    } else if (bid < B_ * 3 * PBLK + 256) {
        ((int4*)counts)[(bid - B_ * 3 * PBLK) * 256 + t] = make_int4(0, 0, 0, 0);
        if (bid == B_ * 3 * PBLK && t == 0) *n_occ = 0;
    }
    grid.sync();

    // ---- phase B: pmax partials (blocks 0..511) ----
    if (bid < B_ * PBLKM) {
        const int blk = bid & (PBLKM - 1), b = bid / PBLKM;
        float* sh = (float*)shraw;       // [0..2]=msh, [4..7]=sm
        if (t == 0) {
            #pragma unroll
            for (int a = 0; a < 3; ++a) {
                float tt = 0.f;
                #pragma unroll
                for (int k = 0; k < PBLK; ++k) tt += pmean[(b * 3 + a) * PBLK + k];
                sh[a] = tt / (float)N_;
            }
        }
        __syncthreads();
        const float mx = sh[0], my = sh[1], mz = sh[2];
        const float4* px = (const float4*)(coords + (size_t)b * 3 * N_ + (size_t)blk * PTS_PER_BLKM);
        const float4* py = px + N_ / 4;
        const float4* pz = px + 2 * (N_ / 4);
        float4 x = px[t], y = py[t], z = pz[t];
        float m = 0.f;
        {
            float x0 = x.x - mx, y0 = y.x - my, z0 = z.x - mz;
            float x1 = x.y - mx, y1 = y.y - my, z1 = z.y - mz;
            float x2 = x.z - mx, y2 = y.z - my, z2 = z.z - mz;
            float x3 = x.w - mx, y3 = y.w - my, z3 = z.w - mz;
            m = fmaxf(m, x0 * x0 + y0 * y0 + z0 * z0);
            m = fmaxf(m, x1 * x1 + y1 * y1 + z1 * z1);
            m = fmaxf(m, x2 * x2 + y2 * y2 + z2 * z2);
            m = fmaxf(m, x3 * x3 + y3 * y3 + z3 * z3);
        }
        #pragma unroll
        for (int off = 32; off >= 1; off >>= 1) m = fmaxf(m, __shfl_down(m, off, 64));
        if (lane == 0) sh[4 + wv] = m;
        __syncthreads();
        if (t == 0)
            pmax[bid] = fmaxf(fmaxf(sh[4], sh[5]), fmaxf(sh[6], sh[7]));
    }
    grid.sync();

    // ---- phase C: voxelize (512 pts per block; 512 | N so one b per block) ----
    {
        const int base = bid * 512;
        const int b = base >> 16;
        float* par = (float*)shraw;        // mx,my,mz,denom
        if (t == 0) {
            #pragma unroll
            for (int a = 0; a < 3; ++a) {
                float tt = 0.f;
                #pragma unroll
                for (int k = 0; k < PBLK; ++k) tt += pmean[(b * 3 + a) * PBLK + k];
                par[a] = tt / (float)N_;
            }
            float mm = 0.f;
            #pragma unroll
            for (int k = 0; k < PBLKM; ++k) mm = fmaxf(mm, pmax[b * PBLKM + k]);
            par[3] = 2.0f * sqrtf(mm);     // EPS == 0; sqrt(max n2) == max norm
        }
        __syncthreads();
        const float denom = par[3];
        const float mx = par[0], my = par[1], mz = par[2];
        const float* pc = coords + (size_t)b * 3 * N_;
        #pragma unroll
        for (int k = 0; k < 2; ++k) {
            const int idx = base + k * 256 + t;
            const int n = idx & (N_ - 1);
            const float pm[3] = {mx, my, mz};
            int fl = 0;
            #pragma unroll
            for (int a = 0; a < 3; ++a) {
                float v = (pc[(size_t)a * N_ + n] - pm[a]) / denom + 0.5f;
                v = v * (float)Rr;
                v = fminf(fmaxf(v, 0.0f), (float)(Rr - 1));
                nc_out[(size_t)b * 3 * N_ + (size_t)a * N_ + n] = v;
                fl = fl * Rr + (int)rintf(v);   // RNE == jnp.round
            }
            flat[idx] = fl;
            atomicAdd(&counts[b * R3 + fl], 1);
        }
    }
    grid.sync();

    // ---- phase D: per-batch scan + compaction (blocks 0..7; 4 chunks of 8192, carry) ----
    if (bid < B_) {
        const int b = bid;
        int* ish = (int*)shraw;  // [0..3]wsum [4..7]wnz [8..11]woffs [12..15]woffn [16]base [17]tot
        int carry = 0;
        for (int ch = 0; ch < 4; ++ch) {
            const int v0 = ch * 8192;
            int local[32];
            const int4* c4 = (const int4*)(counts + b * R3 + v0);
            int s = 0, nz = 0;
            #pragma unroll
            for (int k = 0; k < 8; ++k) {
                const int4 v = c4[t * 8 + k];
                local[k * 4 + 0] = v.x; local[k * 4 + 1] = v.y;
                local[k * 4 + 2] = v.z; local[k * 4 + 3] = v.w;
                s  += v.x + v.y + v.z + v.w;
                nz += (v.x > 0) + (v.y > 0) + (v.z > 0) + (v.w > 0);
            }
            const int s_own = s, nz_own = nz;
            #pragma unroll
            for (int off = 1; off < 64; off <<= 1) {
                const int vs = __shfl_up(s, off, 64);
                const int vn = __shfl_up(nz, off, 64);
                if (lane >= off) { s += vs; nz += vn; }
            }
            if (lane == 63) { ish[wv] = s; ish[4 + wv] = nz; }
            __syncthreads();
            if (t == 0) {
                int rs = 0, rn = 0;
                #pragma unroll
                for (int w = 0; w < 4; ++w) {
                    ish[8 + w] = rs; ish[12 + w] = rn;
                    rs += ish[w]; rn += ish[4 + w];
                }
                ish[17] = rs;
                ish[16] = atomicAdd(n_occ, rn);
            }
            __syncthreads();
            int run  = carry + ish[8 + wv] + (s - s_own);
            int slot = ish[16] + ish[12 + wv] + (nz - nz_own);
            int* cur = cursor + b * R3 + v0 + t * 32;
            #pragma unroll
            for (int k = 0; k < 32; ++k) {
                cur[k] = run;
                if (local[k] > 0)
                    clist[slot++] = make_int4(b * R3 + v0 + t * 32 + k, run, local[k], 0);
                run += local[k];
            }
            carry += ish[17];
            __syncthreads();
        }
    }
    grid.sync();

    // ---- phase E: fused pos-assign + fp8 transpose (8 tiles per block) ----
    {
        unsigned char (*tileS)[68] = (unsigned char (*)[68])shraw;   // 64*68 = 4352 B
        int* pos_s = (int*)(shraw + 4352);
        for (int tt = 0; tt < 8; ++tt) {
            __syncthreads();                    // protect tileS/pos_s reuse
            const int tile = bid * 8 + tt;
            const int b  = tile >> 10;
            const int n0 = (tile & 1023) << 6;
            if (t < 64) pos_s[t] = atomicAdd(&cursor[b * R3 + flat[b * N_ + n0 + t]], 1);
            const int g = t & 15, c0 = t >> 4;
            #pragma unroll
            for (int it = 0; it < 4; ++it) {
                const int c = it * 16 + c0;
                const f32x4 v = __builtin_nontemporal_load(
                    (const f32x4*)(features + ((size_t)b * C_ + c) * N_ + n0 + g * 4));
                *(unsigned int*)&tileS[c][g * 4] = pack4_fp8(v.x, v.y, v.z, v.w);
            }
            __syncthreads();
            const int j = t >> 2, q = t & 3, cb = q * 16;
            unsigned int w0 = (unsigned int)tileS[cb + 0][j] | ((unsigned int)tileS[cb + 1][j] << 8) |
                              ((unsigned int)tileS[cb + 2][j] << 16) | ((unsigned int)tileS[cb + 3][j] << 24);
            unsigned int w1 = (unsigned int)tileS[cb + 4][j] | ((unsigned int)tileS[cb + 5][j] << 8) |
                              ((unsigned int)tileS[cb + 6][j] << 16) | ((unsigned int)tileS[cb + 7][j] << 24);
            unsigned int w2 = (unsigned int)tileS[cb + 8][j] | ((unsigned int)tileS[cb + 9][j] << 8) |
                              ((unsigned int)tileS[cb + 10][j] << 16) | ((unsigned int)tileS[cb + 11][j] << 24);
            unsigned int w3 = (unsigned int)tileS[cb + 12][j] | ((unsigned int)tileS[cb + 13][j] << 8) |
                              ((unsigned int)tileS[cb + 14][j] << 16) | ((unsigned int)tileS[cb + 15][j] << 24);
            *(uint4*)(ftS + ((size_t)b * N_ + pos_s[j]) * C_ + cb) = make_uint4(w0, w1, w2, w3);
        }
    }
    grid.sync();

    // ---- phase F: per-voxel segmented sum (grid-stride over clist; 4096 waves) ----
    {
        const int gw = bid * 4 + wv;
        const int nw = gridDim.x * 4;
        const int tot = *n_occ;
        const int sub = lane >> 4;
        const int g   = lane & 15;
        for (int e = gw; e < tot; e += nw) {
            const int4 ent = clist[e];
            const int wid = ent.x, start = ent.y, cnt = ent.z;
            const int b = wid >> 15;
            const unsigned char* base = ftS + ((size_t)b * N_ + start) * C_ + g * 4;
            float a0 = 0.f, a1 = 0.f, a2 = 0.f, a3 = 0.f;
            #pragma unroll 2
            for (int tt = sub; tt < cnt; tt += 4) {
                const unsigned int u = *(const unsigned int*)(base + (size_t)tt * C_);
                const float4 f = unpack4_fp8(u);
                a0 += f.x; a1 += f.y; a2 += f.z; a3 += f.w;
            }
            #pragma unroll
            for (int off = 16; off <= 32; off <<= 1) {
                a0 += __shfl_xor(a0, off, 64);
                a1 += __shfl_xor(a1, off, 64);
                a2 += __shfl_xor(a2, off, 64);
                a3 += __shfl_xor(a3, off, 64);
            }
            if (sub == 0)
                *(float4*)(acc + (size_t)wid * C_ + g * 4) = make_float4(a0, a1, a2, a3);
        }
    }
    grid.sync();

    // ---- phase G: transpose acc/max(cnt,1) -> out (4 chunks per block) ----
    {
        float (*tile)[65] = (float (*)[65])shraw;              // 16640 B
        float* cnt_s = (float*)(shraw + 16640);                // 256 B
        int*   occ   = (int*)(shraw + 16640 + 256);            // 256 B
        for (int k = 0; k < 4; ++k) {
            __syncthreads();                    // protect reuse
            const int chunk = bid * 4 + k;
            const int b  = chunk >> 9;
            const int v0 = (chunk & 511) * 64;
            if (t < 64) {
                const int c = counts[b * R3 + v0 + t];
                occ[t]   = c;
                cnt_s[t] = fmaxf((float)c, 1.0f);
            }
            __syncthreads();
            const int row0 = t >> 6;
            #pragma unroll
            for (int it = 0; it < 16; ++it) {
                const int vi = row0 + it * 4;
                tile[vi][lane] = occ[vi] ? acc[((size_t)(b * R3 + v0 + vi)) * C_ + lane] : 0.f;
            }
            __syncthreads();
            #pragma unroll
            for (int it = 0; it < 16; ++it) {
                const int c = row0 + it * 4;
                out[((size_t)b * C_ + c) * R3 + v0 + lane] = tile[lane][c] / cnt_s[lane];
            }
        }
    }
}

// ============ multi-kernel path (round-17 proven, used if coop launch unavailable) ============
__global__ void pmean_zero_kernel(const float* __restrict__ coords,
                                  float* __restrict__ pmean,
                                  int4* __restrict__ counts4,
                                  int* __restrict__ n_occ) {
    if (blockIdx.x >= B_ * 3 * PBLK) {
        const int zb = blockIdx.x - B_ * 3 * PBLK;
        counts4[zb * 256 + threadIdx.x] = make_int4(0, 0, 0, 0);
        if (zb == 0 && threadIdx.x == 0) *n_occ = 0;
        return;
    }
    const int blk = blockIdx.x & (PBLK - 1);
    const int ba  = blockIdx.x / PBLK;
    const float4* p = (const float4*)(coords + (size_t)ba * N_ + (size_t)blk * PTS_PER_BLK);
    float s = 0.f;
    #pragma unroll
    for (int k = 0; k < PTS_PER_BLK / 4 / 256; ++k) {
        float4 v = p[k * 256 + threadIdx.x];
        s += (v.x + v.y) + (v.z + v.w);
    }
    #pragma unroll
    for (int off = 32; off >= 1; off >>= 1) s += __shfl_down(s, off, 64);
    __shared__ float sm[4];
    if ((threadIdx.x & 63) == 0) sm[threadIdx.x >> 6] = s;
    __syncthreads();
    if (threadIdx.x == 0) pmean[blockIdx.x] = sm[0] + sm[1] + sm[2] + sm[3];
}

__global__ void partial_max_kernel(const float* __restrict__ coords,
                                   const float* __restrict__ pmean,
                                   float* __restrict__ pmax) {
    const int blk = blockIdx.x & (PBLKM - 1);
    const int b   = blockIdx.x / PBLKM;
    __shared__ float msh[3];
    if (threadIdx.x == 0) {
        #pragma unroll
        for (int a = 0; a < 3; ++a) {
            float t = 0.f;
            #pragma unroll
            for (int k = 0; k < PBLK; ++k) t += pmean[(b * 3 + a) * PBLK + k];
            msh[a] = t / (float)N_;
        }
    }
    __syncthreads();
    const float mx = msh[0], my = msh[1], mz = msh[2];
    const float4* px = (const float4*)(coords + (size_t)b * 3 * N_ + (size_t)blk * PTS_PER_BLKM);
    const float4* py = px + N_ / 4;
    const float4* pz = px + 2 * (N_ / 4);
    const int i = threadIdx.x;
    float4 x = px[i], y = py[i], z = pz[i];
    float m = 0.f;
    {
        float x0 = x.x - mx, y0 = y.x - my, z0 = z.x - mz;
        float x1 = x.y - mx, y1 = y.y - my, z1 = z.y - mz;
        float x2 = x.z - mx, y2 = y.z - my, z2 = z.z - mz;
        float x3 = x.w - mx, y3 = y.w - my, z3 = z.w - mz;
        m = fmaxf(m, x0 * x0 + y0 * y0 + z0 * z0);
        m = fmaxf(m, x1 * x1 + y1 * y1 + z1 * z1);
        m = fmaxf(m, x2 * x2 + y2 * y2 + z2 * z2);
        m = fmaxf(m, x3 * x3 + y3 * y3 + z3 * z3);
    }
    #pragma unroll
    for (int off = 32; off >= 1; off >>= 1) m = fmaxf(m, __shfl_down(m, off, 64));
    __shared__ float sm[4];
    if ((threadIdx.x & 63) == 0) sm[threadIdx.x >> 6] = m;
    __syncthreads();
    if (threadIdx.x == 0)
        pmax[blockIdx.x] = fmaxf(fmaxf(sm[0], sm[1]), fmaxf(sm[2], sm[3]));
}

__global__ void voxelize_kernel(const float* __restrict__ coords,
                                const float* __restrict__ pmean,
                                const float* __restrict__ pmax,
                                float* __restrict__ nc_out,
                                int* __restrict__ flat_out,
                                int* __restrict__ counts) {
    const int idx = blockIdx.x * blockDim.x + threadIdx.x;
    const int b = idx >> 16;
    const int n = idx & (N_ - 1);
    __shared__ float par[4];
    if (threadIdx.x == 0) {
        #pragma unroll
        for (int a = 0; a < 3; ++a) {
            float t = 0.f;
            #pragma unroll
            for (int k = 0; k < PBLK; ++k) t += pmean[(b * 3 + a) * PBLK + k];
            par[a] = t / (float)N_;
        }
        float mm = 0.f;
        #pragma unroll
        for (int k = 0; k < PBLKM; ++k) mm = fmaxf(mm, pmax[b * PBLKM + k]);
        par[3] = 2.0f * sqrtf(mm);
    }
    __syncthreads();
    const float* pc = coords + (size_t)b * 3 * N_;
    const float denom = par[3];
    int flat = 0;
    #pragma unroll
    for (int a = 0; a < 3; ++a) {
        float v = (pc[(size_t)a * N_ + n] - par[a]) / denom + 0.5f;
        v = v * (float)Rr;
        v = fminf(fmaxf(v, 0.0f), (float)(Rr - 1));
        nc_out[(size_t)b * 3 * N_ + (size_t)a * N_ + n] = v;
        flat = flat * Rr + (int)rintf(v);
    }
    flat_out[idx] = flat;
    atomicAdd(&counts[b * R3 + flat], 1);
}

__global__ void scan_compact_kernel(const int* __restrict__ counts,
                                    int* __restrict__ cursor,
                                    int4* __restrict__ clist,
                                    int* __restrict__ n_occ) {
    const int b = blockIdx.x;
    const int t = threadIdx.x;
    const int lane = t & 63, wv = t >> 6;
    constexpr int PER = R3 / 1024;
    int local[PER];
    const int4* c4 = (const int4*)(counts + b * R3);
    int s = 0, nz = 0;
    #pragma unroll
    for (int k = 0; k < PER / 4; ++k) {
        const int4 v = c4[t * (PER / 4) + k];
        local[k * 4 + 0] = v.x; local[k * 4 + 1] = v.y;
        local[k * 4 + 2] = v.z; local[k * 4 + 3] = v.w;
        s  += v.x + v.y + v.z + v.w;
        nz += (v.x > 0) + (v.y > 0) + (v.z > 0) + (v.w > 0);
    }
    const int s_own = s, nz_own = nz;
    #pragma unroll
    for (int off = 1; off < 64; off <<= 1) {
        const int vs = __shfl_up(s, off, 64);
        const int vn = __shfl_up(nz, off, 64);
        if (lane >= off) { s += vs; nz += vn; }
    }
    __shared__ int wsum[16], wnz[16], woffs[16], woffn[16];
    __shared__ int basesh;
    if (lane == 63) { wsum[wv] = s; wnz[wv] = nz; }
    __syncthreads();
    if (t < 16) {
        const int as = wsum[t], an = wnz[t];
        int is = as, in_ = an;
        #pragma unroll
        for (int off = 1; off < 16; off <<= 1) {
            const int vs = __shfl_up(is, off, 16);
            const int vn = __shfl_up(in_, off, 16);
            if (t >= off) { is += vs; in_ += vn; }
        }
        woffs[t] = is - as;
        woffn[t] = in_ - an;
        if (t == 15) basesh = atomicAdd(n_occ, in_);
    }
    __syncthreads();
    int run  = woffs[wv] + (s - s_own);
    int slot = basesh + woffn[wv] + (nz - nz_own);
    int* cur = cursor + b * R3 + t * PER;
    #pragma unroll
    for (int k = 0; k < PER; ++k) {
        cur[k] = run;
        if (local[k] > 0) clist[slot++] = make_int4(b * R3 + t * PER + k, run, local[k], 0);
        run += local[k];
    }
}

__global__ void sorted_transpose_ids_kernel(const float* __restrict__ features,
                                            const int* __restrict__ flat,
                                            int* __restrict__ cursor,
                                            unsigned char* __restrict__ ftS) {
    const int tile = blockIdx.x & 1023;
    const int b    = blockIdx.x >> 10;
    const int n0   = tile * 64;
    __shared__ unsigned char tileS[64][68];
    __shared__ int pos_s[64];
    const int t = threadIdx.x;
    if (t < 64) {
        const int f = flat[b * N_ + n0 + t];
        pos_s[t] = atomicAdd(&cursor[b * R3 + f], 1);
    }
    const int g  = t & 15;
    const int c0 = t >> 4;
    #pragma unroll
    for (int it = 0; it < 4; ++it) {
        const int c = it * 16 + c0;
        const f32x4 v = __builtin_nontemporal_load(
            (const f32x4*)(features + ((size_t)b * C_ + c) * N_ + n0 + g * 4));
        *(unsigned int*)&tileS[c][g * 4] = pack4_fp8(v.x, v.y, v.z, v.w);
    }
    __syncthreads();
    const int j = t >> 2, q = t & 3, cb = q * 16;
    unsigned int w0 = (unsigned int)tileS[cb + 0][j] | ((unsigned int)tileS[cb + 1][j] << 8) |
                      ((unsigned int)tileS[cb + 2][j] << 16) | ((unsigned int)tileS[cb + 3][j] << 24);
    unsigned int w1 = (unsigned int)tileS[cb + 4][j] | ((unsigned int)tileS[cb + 5][j] << 8) |
                      ((unsigned int)tileS[cb + 6][j] << 16) | ((unsigned int)tileS[cb + 7][j] << 24);
    unsigned int w2 = (unsigned int)tileS[cb + 8][j] | ((unsigned int)tileS[cb + 9][j] << 8) |
                      ((unsigned int)tileS[cb + 10][j] << 16) | ((unsigned int)tileS[cb + 11][j] << 24);
    unsigned int w3 = (unsigned int)tileS[cb + 12][j] | ((unsigned int)tileS[cb + 13][j] << 8) |
                      ((unsigned int)tileS[cb + 14][j] << 16) | ((unsigned int)tileS[cb + 15][j] << 24);
    *(uint4*)(ftS + ((size_t)b * N_ + pos_s[j]) * C_ + cb) = make_uint4(w0, w1, w2, w3);
}

__global__ void voxel_sum_compact_kernel(const unsigned char* __restrict__ ftS,
                                         const int4* __restrict__ clist,
                                         const int* __restrict__ n_occ,
                                         float* __restrict__ acc) {
    const int lane = threadIdx.x & 63;
    const int gw = blockIdx.x * (blockDim.x >> 6) + (threadIdx.x >> 6);
    const int nw = gridDim.x * (blockDim.x >> 6);
    const int tot = *n_occ;
    const int sub = lane >> 4;
    const int g   = lane & 15;
    for (int e = gw; e < tot; e += nw) {
        const int4 ent = clist[e];
        const int wid = ent.x, start = ent.y, cnt = ent.z;
        const int b = wid >> 15;
        const unsigned char* base = ftS + ((size_t)b * N_ + start) * C_ + g * 4;
        float a0 = 0.f, a1 = 0.f, a2 = 0.f, a3 = 0.f;
        #pragma unroll 2
        for (int t = sub; t < cnt; t += 4) {
            const unsigned int u = *(const unsigned int*)(base + (size_t)t * C_);
            const float4 f = unpack4_fp8(u);
            a0 += f.x; a1 += f.y; a2 += f.z; a3 += f.w;
        }
        #pragma unroll
        for (int off = 16; off <= 32; off <<= 1) {
            a0 += __shfl_xor(a0, off, 64);
            a1 += __shfl_xor(a1, off, 64);
            a2 += __shfl_xor(a2, off, 64);
            a3 += __shfl_xor(a3, off, 64);
        }
        if (sub == 0) {
            *(float4*)(acc + (size_t)wid * C_ + g * 4) = make_float4(a0, a1, a2, a3);
        }
    }
}

__global__ void transpose_finalize_kernel(const float* __restrict__ acc,
                                          const int* __restrict__ counts,
                                          float* __restrict__ out) {
    const int chunk = blockIdx.x;
    const int b  = chunk >> 9;
    const int v0 = (chunk & 511) * 64;
    __shared__ float tile[64][65];
    __shared__ float cnt_s[64];
    __shared__ int   occ[64];
    const int lane = threadIdx.x & 63, row0 = threadIdx.x >> 6;
    if (threadIdx.x < 64) {
        const int c = counts[b * R3 + v0 + threadIdx.x];
        occ[threadIdx.x]   = c;
        cnt_s[threadIdx.x] = fmaxf((float)c, 1.0f);
    }
    __syncthreads();
    #pragma unroll
    for (int it = 0; it < 16; ++it) {
        const int vi = row0 + it * 4;
        tile[vi][lane] = occ[vi] ? acc[((size_t)(b * R3 + v0 + vi)) * C_ + lane] : 0.f;
    }
    __syncthreads();
    #pragma unroll
    for (int it = 0; it < 16; ++it) {
        const int c = row0 + it * 4;
        out[((size_t)b * C_ + c) * R3 + v0 + lane] = tile[lane][c] / cnt_s[lane];
    }
}

// ============ FALLBACK PATH (round-1 style, ws too small) ============
__global__ void mean_kernel(const float* __restrict__ coords,
                            float* __restrict__ mean_out) {
    const int ba = blockIdx.x;
    const float* p = coords + (size_t)ba * N_;
    float s = 0.f;
    for (int i = threadIdx.x; i < N_; i += blockDim.x) s += p[i];
    #pragma unroll
    for (int off = 32; off >= 1; off >>= 1) s += __shfl_down(s, off, 64);
    __shared__ float sm[4];
    if ((threadIdx.x & 63) == 0) sm[threadIdx.x >> 6] = s;
    __syncthreads();
    if (threadIdx.x == 0) mean_out[ba] = (sm[0] + sm[1] + sm[2] + sm[3]) / (float)N_;
}

__global__ void maxnorm_kernel(const float* __restrict__ coords,
                               const float* __restrict__ mean,
                               float* __restrict__ maxn) {
    const int b = blockIdx.x;
    const float* p = coords + (size_t)b * 3 * N_;
    const float mx = mean[b * 3 + 0], my = mean[b * 3 + 1], mz = mean[b * 3 + 2];
    float m = 0.f;
    for (int i = threadIdx.x; i < N_; i += blockDim.x) {
        const float x = p[i] - mx, y = p[N_ + i] - my, z = p[2 * N_ + i] - mz;
        m = fmaxf(m, x * x + y * y + z * z);
    }
    #pragma unroll
    for (int off = 32; off >= 1; off >>= 1) m = fmaxf(m, __shfl_down(m, off, 64));
    __shared__ float sm[16];
    if ((threadIdx.x & 63) == 0) sm[threadIdx.x >> 6] = m;
    __syncthreads();
    if (threadIdx.x == 0) {
        float t = sm[0];
        const int nw = blockDim.x >> 6;
        for (int w = 1; w < nw; ++w) t = fmaxf(t, sm[w]);
        maxn[b] = sqrtf(t);
    }
}

__global__ void scatter_kernel(const float* __restrict__ coords,
                               const float* __restrict__ features,
                               const float* __restrict__ mean,
                               const float* __restrict__ maxn,
                               float* __restrict__ out,
                               float* __restrict__ nc_out,
                               float* __restrict__ counts) {
    const int idx = blockIdx.x * blockDim.x + threadIdx.x;
    if (idx >= B_ * N_) return;
    const int b = idx >> 16;
    const int n = idx & (N_ - 1);
    const float* pc = coords + (size_t)b * 3 * N_;
    const float denom = 2.0f * maxn[b];
    int flat = 0;
    #pragma unroll
    for (int a = 0; a < 3; ++a) {
        float v = (pc[(size_t)a * N_ + n] - mean[b * 3 + a]) / denom + 0.5f;
        v = v * (float)Rr;
        v = fminf(fmaxf(v, 0.0f), (float)(Rr - 1));
        nc_out[(size_t)b * 3 * N_ + (size_t)a * N_ + n] = v;
        flat = flat * Rr + (int)rintf(v);
    }
    atomicAdd(&counts[b * R3 + flat], 1.0f);
    const float* pf = features + (size_t)b * C_ * N_ + n;
    float* po = out + (size_t)b * C_ * R3 + flat;
    #pragma unroll 4
    for (int c = 0; c < C_; ++c) atomicAdd(po + (size_t)c * R3, pf[(size_t)c * N_]);
}

__global__ void finalize_kernel(float* __restrict__ out,
                                const float* __restrict__ counts) {
    const int idx = blockIdx.x * blockDim.x + threadIdx.x;
    if (idx >= B_ * C_ * R3) return;
    const int b = idx / (C_ * R3);
    const int v = idx & (R3 - 1);
    out[idx] = out[idx] / fmaxf(counts[b * R3 + v], 1.0f);
}

extern "C" void kernel_launch(void* const* d_in, const int* in_sizes, int n_in,
                              void* d_out, int out_size, void* d_ws, size_t ws_size,
                              hipStream_t stream) {
    const float* features = (const float*)d_in[0];
    const float* coords   = (const float*)d_in[1];

    float* out    = (float*)d_out;
    float* nc_out = out + (size_t)B_ * C_ * R3;

    const size_t accB   = (size_t)B_ * R3 * C_ * sizeof(float);
    const size_t cntB   = (size_t)B_ * R3 * sizeof(int);
    const size_t curB   = cntB;
    const size_t flatB  = (size_t)B_ * N_ * sizeof(int);
    const size_t clistB = (size_t)B_ * R3 * sizeof(int4);
    const size_t smallB = 16384;
    const size_t ftsB   = (size_t)B_ * N_ * C_;

    const size_t need = accB + cntB + curB + flatB + clistB + smallB + ftsB;
    const int pts = B_ * N_;

    if (ws_size >= need) {
        char* w = (char*)d_ws;
        float* acc    = (float*)w;                 w += accB;
        int*   counts = (int*)w;                   w += cntB;
        int*   cursor = (int*)w;                   w += curB;
        int*   flat   = (int*)w;                   w += flatB;
        int4*  clist  = (int4*)w;                  w += clistB;
        int*   n_occ  = (int*)w;
        float* pmean  = (float*)(w + 16);
        float* pmax   = pmean + B_ * 3 * PBLK;
        w += smallB;
        unsigned char* ftS = (unsigned char*)w;

        void* args[] = { (void*)&features, (void*)&coords, (void*)&nc_out, (void*)&out,
                         (void*)&acc, (void*)&counts, (void*)&cursor, (void*)&flat,
                         (void*)&clist, (void*)&n_occ, (void*)&pmean, (void*)&pmax,
                         (void*)&ftS };
        hipError_t err = hipLaunchCooperativeKernel(
            (void*)mega_kernel, dim3(1024), dim3(256), args, 0, stream);

        if (err != hipSuccess) {
            (void)hipGetLastError();   // clear error state, fall back to multi-kernel
            pmean_zero_kernel<<<B_ * 3 * PBLK + 256, 256, 0, stream>>>(
                coords, pmean, (int4*)counts, n_occ);
            partial_max_kernel<<<B_ * PBLKM, 256, 0, stream>>>(coords, pmean, pmax);
            voxelize_kernel<<<pts / 256, 256, 0, stream>>>(
                coords, pmean, pmax, nc_out, flat, counts);
            scan_compact_kernel<<<B_, 1024, 0, stream>>>(counts, cursor, clist, n_occ);
            sorted_transpose_ids_kernel<<<B_ * (N_ / 64), 256, 0, stream>>>(
                features, flat, cursor, ftS);
            voxel_sum_compact_kernel<<<2048, 256, 0, stream>>>(ftS, clist, n_occ, acc);
            transpose_finalize_kernel<<<B_ * (R3 / 64), 256, 0, stream>>>(acc, counts, out);
        }
    } else {
        float* counts = (float*)d_ws;
        float* mean   = counts + (size_t)B_ * R3;
        float* maxn   = mean + B_ * 3;

        hipMemsetAsync(d_out, 0, (size_t)B_ * C_ * R3 * sizeof(float), stream);
        hipMemsetAsync(d_ws, 0, ((size_t)B_ * R3 + B_ * 3 + B_) * sizeof(float), stream);

        mean_kernel<<<B_ * 3, 256, 0, stream>>>(coords, mean);
        maxnorm_kernel<<<B_, 1024, 0, stream>>>(coords, mean, maxn);
        scatter_kernel<<<(pts + 255) / 256, 256, 0, stream>>>(
            coords, features, mean, maxn, out, nc_out, counts);
        finalize_kernel<<<(B_ * C_ * R3 + 255) / 256, 256, 0, stream>>>(out, counts);
    }
}

// Round 19
// 158.787 us; speedup vs baseline: 5.2086x; 5.2086x over previous
//
#include <hip/hip_runtime.h>
#include <hip/hip_bf16.h>
#include <hip/hip_fp8.h>
#include <cstdint>

static constexpr int B_  = 8;
static constexpr int C_  = 64;
static constexpr int N_  = 65536;
static constexpr int Rr  = 32;
static constexpr int R3  = Rr * Rr * Rr;        // 32768 = 2^15
static constexpr int PBLK  = 16;
static constexpr int PBLKM = 64;
static constexpr int PTS_PER_BLK  = N_ / PBLK;  // 4096
static constexpr int PTS_PER_BLKM = N_ / PBLKM; // 1024

typedef float f32x4 __attribute__((ext_vector_type(4)));

__device__ __forceinline__ unsigned int pack4_fp8(float a, float b, float c, float d) {
    __hip_fp8x4_e4m3 q(make_float4(a, b, c, d));
    return *reinterpret_cast<unsigned int*>(&q);
}
__device__ __forceinline__ float4 unpack4_fp8(unsigned int u) {
    __hip_fp8x4_e4m3 q;
    *reinterpret_cast<unsigned int*>(&q) = u;
    return (float4)q;
}

// ---------------- kernel A: partial mean + zero counts/n_occ ----------------
__global__ void pmean_zero_kernel(const float* __restrict__ coords,
                                  float* __restrict__ pmean,
                                  int4* __restrict__ counts4,
                                  int* __restrict__ n_occ) {
    if (blockIdx.x >= B_ * 3 * PBLK) {
        const int zb = blockIdx.x - B_ * 3 * PBLK;
        counts4[zb * 256 + threadIdx.x] = make_int4(0, 0, 0, 0);
        if (zb == 0 && threadIdx.x == 0) *n_occ = 0;
        return;
    }
    const int blk = blockIdx.x & (PBLK - 1);
    const int ba  = blockIdx.x / PBLK;
    const float4* p = (const float4*)(coords + (size_t)ba * N_ + (size_t)blk * PTS_PER_BLK);
    float s = 0.f;
    #pragma unroll
    for (int k = 0; k < PTS_PER_BLK / 4 / 256; ++k) {
        float4 v = p[k * 256 + threadIdx.x];
        s += (v.x + v.y) + (v.z + v.w);
    }
    #pragma unroll
    for (int off = 32; off >= 1; off >>= 1) s += __shfl_down(s, off, 64);
    __shared__ float sm[4];
    if ((threadIdx.x & 63) == 0) sm[threadIdx.x >> 6] = s;
    __syncthreads();
    if (threadIdx.x == 0) pmean[blockIdx.x] = sm[0] + sm[1] + sm[2] + sm[3];
}

// ---------------- kernel B: partial max of centered norm^2 ----------------
__global__ void partial_max_kernel(const float* __restrict__ coords,
                                   const float* __restrict__ pmean,
                                   float* __restrict__ pmax) {
    const int blk = blockIdx.x & (PBLKM - 1);
    const int b   = blockIdx.x / PBLKM;
    __shared__ float msh[3];
    if (threadIdx.x == 0) {
        #pragma unroll
        for (int a = 0; a < 3; ++a) {
            float t = 0.f;
            #pragma unroll
            for (int k = 0; k < PBLK; ++k) t += pmean[(b * 3 + a) * PBLK + k];
            msh[a] = t / (float)N_;
        }
    }
    __syncthreads();
    const float mx = msh[0], my = msh[1], mz = msh[2];
    const float4* px = (const float4*)(coords + (size_t)b * 3 * N_ + (size_t)blk * PTS_PER_BLKM);
    const float4* py = px + N_ / 4;
    const float4* pz = px + 2 * (N_ / 4);
    const int i = threadIdx.x;
    float4 x = px[i], y = py[i], z = pz[i];
    float m = 0.f;
    {
        float x0 = x.x - mx, y0 = y.x - my, z0 = z.x - mz;
        float x1 = x.y - mx, y1 = y.y - my, z1 = z.y - mz;
        float x2 = x.z - mx, y2 = y.z - my, z2 = z.z - mz;
        float x3 = x.w - mx, y3 = y.w - my, z3 = z.w - mz;
        m = fmaxf(m, x0 * x0 + y0 * y0 + z0 * z0);
        m = fmaxf(m, x1 * x1 + y1 * y1 + z1 * z1);
        m = fmaxf(m, x2 * x2 + y2 * y2 + z2 * z2);
        m = fmaxf(m, x3 * x3 + y3 * y3 + z3 * z3);
    }
    #pragma unroll
    for (int off = 32; off >= 1; off >>= 1) m = fmaxf(m, __shfl_down(m, off, 64));
    __shared__ float sm[4];
    if ((threadIdx.x & 63) == 0) sm[threadIdx.x >> 6] = m;
    __syncthreads();
    if (threadIdx.x == 0)
        pmax[blockIdx.x] = fmaxf(fmaxf(sm[0], sm[1]), fmaxf(sm[2], sm[3]));
}

// ---------------- kernel C: voxelize ----------------
__global__ void voxelize_kernel(const float* __restrict__ coords,
                                const float* __restrict__ pmean,
                                const float* __restrict__ pmax,
                                float* __restrict__ nc_out,
                                int* __restrict__ flat_out,
                                int* __restrict__ counts) {
    const int idx = blockIdx.x * blockDim.x + threadIdx.x;
    const int b = idx >> 16;
    const int n = idx & (N_ - 1);
    __shared__ float par[4];
    if (threadIdx.x == 0) {
        #pragma unroll
        for (int a = 0; a < 3; ++a) {
            float t = 0.f;
            #pragma unroll
            for (int k = 0; k < PBLK; ++k) t += pmean[(b * 3 + a) * PBLK + k];
            par[a] = t / (float)N_;
        }
        float mm = 0.f;
        #pragma unroll
        for (int k = 0; k < PBLKM; ++k) mm = fmaxf(mm, pmax[b * PBLKM + k]);
        par[3] = 2.0f * sqrtf(mm);
    }
    __syncthreads();
    const float* pc = coords + (size_t)b * 3 * N_;
    const float denom = par[3];
    int flat = 0;
    #pragma unroll
    for (int a = 0; a < 3; ++a) {
        float v = (pc[(size_t)a * N_ + n] - par[a]) / denom + 0.5f;
        v = v * (float)Rr;
        v = fminf(fmaxf(v, 0.0f), (float)(Rr - 1));
        nc_out[(size_t)b * 3 * N_ + (size_t)a * N_ + n] = v;
        flat = flat * Rr + (int)rintf(v);
    }
    flat_out[idx] = flat;
    atomicAdd(&counts[b * R3 + flat], 1);
}

// ---------------- kernel D: per-batch scan + compaction ----------------
__global__ void scan_compact_kernel(const int* __restrict__ counts,
                                    int* __restrict__ cursor,
                                    int4* __restrict__ clist,
                                    int* __restrict__ n_occ) {
    const int b = blockIdx.x;
    const int t = threadIdx.x;
    const int lane = t & 63, wv = t >> 6;
    constexpr int PER = R3 / 1024;
    int local[PER];
    const int4* c4 = (const int4*)(counts + b * R3);
    int s = 0, nz = 0;
    #pragma unroll
    for (int k = 0; k < PER / 4; ++k) {
        const int4 v = c4[t * (PER / 4) + k];
        local[k * 4 + 0] = v.x; local[k * 4 + 1] = v.y;
        local[k * 4 + 2] = v.z; local[k * 4 + 3] = v.w;
        s  += v.x + v.y + v.z + v.w;
        nz += (v.x > 0) + (v.y > 0) + (v.z > 0) + (v.w > 0);
    }
    const int s_own = s, nz_own = nz;
    #pragma unroll
    for (int off = 1; off < 64; off <<= 1) {
        const int vs = __shfl_up(s, off, 64);
        const int vn = __shfl_up(nz, off, 64);
        if (lane >= off) { s += vs; nz += vn; }
    }
    __shared__ int wsum[16], wnz[16], woffs[16], woffn[16];
    __shared__ int basesh;
    if (lane == 63) { wsum[wv] = s; wnz[wv] = nz; }
    __syncthreads();
    if (t < 16) {
        const int as = wsum[t], an = wnz[t];
        int is = as, in_ = an;
        #pragma unroll
        for (int off = 1; off < 16; off <<= 1) {
            const int vs = __shfl_up(is, off, 16);
            const int vn = __shfl_up(in_, off, 16);
            if (t >= off) { is += vs; in_ += vn; }
        }
        woffs[t] = is - as;
        woffn[t] = in_ - an;
        if (t == 15) basesh = atomicAdd(n_occ, in_);
    }
    __syncthreads();
    int run  = woffs[wv] + (s - s_own);
    int slot = basesh + woffn[wv] + (nz - nz_own);
    int* cur = cursor + b * R3 + t * PER;
    #pragma unroll
    for (int k = 0; k < PER; ++k) {
        cur[k] = run;
        if (local[k] > 0) clist[slot++] = make_int4(b * R3 + t * PER + k, run, local[k], 0);
        run += local[k];
    }
}

// ---------------- kernel E: fused pos-assign + fp8 transpose (NT loads, HW cvt) ----------------
__global__ void sorted_transpose_ids_kernel(const float* __restrict__ features,
                                            const int* __restrict__ flat,
                                            int* __restrict__ cursor,
                                            unsigned char* __restrict__ ftS) {
    const int tile = blockIdx.x & 1023;
    const int b    = blockIdx.x >> 10;
    const int n0   = tile * 64;
    __shared__ unsigned char tileS[64][68];
    __shared__ int pos_s[64];
    const int t = threadIdx.x;
    if (t < 64) {
        const int f = flat[b * N_ + n0 + t];
        pos_s[t] = atomicAdd(&cursor[b * R3 + f], 1);
    }
    const int g  = t & 15;
    const int c0 = t >> 4;
    #pragma unroll
    for (int it = 0; it < 4; ++it) {
        const int c = it * 16 + c0;
        const f32x4 v = __builtin_nontemporal_load(
            (const f32x4*)(features + ((size_t)b * C_ + c) * N_ + n0 + g * 4));
        *(unsigned int*)&tileS[c][g * 4] = pack4_fp8(v.x, v.y, v.z, v.w);
    }
    __syncthreads();
    const int j = t >> 2, q = t & 3, cb = q * 16;
    unsigned int w0 = (unsigned int)tileS[cb + 0][j] | ((unsigned int)tileS[cb + 1][j] << 8) |
                      ((unsigned int)tileS[cb + 2][j] << 16) | ((unsigned int)tileS[cb + 3][j] << 24);
    unsigned int w1 = (unsigned int)tileS[cb + 4][j] | ((unsigned int)tileS[cb + 5][j] << 8) |
                      ((unsigned int)tileS[cb + 6][j] << 16) | ((unsigned int)tileS[cb + 7][j] << 24);
    unsigned int w2 = (unsigned int)tileS[cb + 8][j] | ((unsigned int)tileS[cb + 9][j] << 8) |
                      ((unsigned int)tileS[cb + 10][j] << 16) | ((unsigned int)tileS[cb + 11][j] << 24);
    unsigned int w3 = (unsigned int)tileS[cb + 12][j] | ((unsigned int)tileS[cb + 13][j] << 8) |
                      ((unsigned int)tileS[cb + 14][j] << 16) | ((unsigned int)tileS[cb + 15][j] << 24);
    *(uint4*)(ftS + ((size_t)b * N_ + pos_s[j]) * C_ + cb) = make_uint4(w0, w1, w2, w3);
}

// ---------------- kernel F: per-voxel segmented sum ----------------
__global__ void voxel_sum_compact_kernel(const unsigned char* __restrict__ ftS,
                                         const int4* __restrict__ clist,
                                         const int* __restrict__ n_occ,
                                         float* __restrict__ acc) {
    const int lane = threadIdx.x & 63;
    const int gw = blockIdx.x * (blockDim.x >> 6) + (threadIdx.x >> 6);
    const int nw = gridDim.x * (blockDim.x >> 6);
    const int tot = *n_occ;
    const int sub = lane >> 4;
    const int g   = lane & 15;
    for (int e = gw; e < tot; e += nw) {
        const int4 ent = clist[e];
        const int wid = ent.x, start = ent.y, cnt = ent.z;
        const int b = wid >> 15;
        const unsigned char* base = ftS + ((size_t)b * N_ + start) * C_ + g * 4;
        float a0 = 0.f, a1 = 0.f, a2 = 0.f, a3 = 0.f;
        #pragma unroll 2
        for (int t = sub; t < cnt; t += 4) {
            const unsigned int u = *(const unsigned int*)(base + (size_t)t * C_);
            const float4 f = unpack4_fp8(u);
            a0 += f.x; a1 += f.y; a2 += f.z; a3 += f.w;
        }
        #pragma unroll
        for (int off = 16; off <= 32; off <<= 1) {
            a0 += __shfl_xor(a0, off, 64);
            a1 += __shfl_xor(a1, off, 64);
            a2 += __shfl_xor(a2, off, 64);
            a3 += __shfl_xor(a3, off, 64);
        }
        if (sub == 0) {
            *(float4*)(acc + (size_t)wid * C_ + g * 4) = make_float4(a0, a1, a2, a3);
        }
    }
}

// ---------------- kernel G: transpose/divide -> out (NT stores: out is write-once) ----------------
__global__ void transpose_finalize_kernel(const float* __restrict__ acc,
                                          const int* __restrict__ counts,
                                          float* __restrict__ out) {
    const int chunk = blockIdx.x;
    const int b  = chunk >> 9;
    const int v0 = (chunk & 511) * 64;
    __shared__ float tile[64][65];
    __shared__ float cnt_s[64];
    __shared__ int   occ[64];
    const int lane = threadIdx.x & 63, row0 = threadIdx.x >> 6;
    if (threadIdx.x < 64) {
        const int c = counts[b * R3 + v0 + threadIdx.x];
        occ[threadIdx.x]   = c;
        cnt_s[threadIdx.x] = fmaxf((float)c, 1.0f);
    }
    __syncthreads();
    #pragma unroll
    for (int it = 0; it < 16; ++it) {
        const int vi = row0 + it * 4;
        tile[vi][lane] = occ[vi] ? acc[((size_t)(b * R3 + v0 + vi)) * C_ + lane] : 0.f;
    }
    __syncthreads();
    #pragma unroll
    for (int it = 0; it < 16; ++it) {
        const int c = row0 + it * 4;
        __builtin_nontemporal_store(tile[lane][c] / cnt_s[lane],
                                    out + ((size_t)b * C_ + c) * R3 + v0 + lane);
    }
}

// ============ FALLBACK PATH (round-1 style, ws too small) ============
__global__ void mean_kernel(const float* __restrict__ coords,
                            float* __restrict__ mean_out) {
    const int ba = blockIdx.x;
    const float* p = coords + (size_t)ba * N_;
    float s = 0.f;
    for (int i = threadIdx.x; i < N_; i += blockDim.x) s += p[i];
    #pragma unroll
    for (int off = 32; off >= 1; off >>= 1) s += __shfl_down(s, off, 64);
    __shared__ float sm[4];
    if ((threadIdx.x & 63) == 0) sm[threadIdx.x >> 6] = s;
    __syncthreads();
    if (threadIdx.x == 0) mean_out[ba] = (sm[0] + sm[1] + sm[2] + sm[3]) / (float)N_;
}

__global__ void maxnorm_kernel(const float* __restrict__ coords,
                               const float* __restrict__ mean,
                               float* __restrict__ maxn) {
    const int b = blockIdx.x;
    const float* p = coords + (size_t)b * 3 * N_;
    const float mx = mean[b * 3 + 0], my = mean[b * 3 + 1], mz = mean[b * 3 + 2];
    float m = 0.f;
    for (int i = threadIdx.x; i < N_; i += blockDim.x) {
        const float x = p[i] - mx, y = p[N_ + i] - my, z = p[2 * N_ + i] - mz;
        m = fmaxf(m, x * x + y * y + z * z);
    }
    #pragma unroll
    for (int off = 32; off >= 1; off >>= 1) m = fmaxf(m, __shfl_down(m, off, 64));
    __shared__ float sm[16];
    if ((threadIdx.x & 63) == 0) sm[threadIdx.x >> 6] = m;
    __syncthreads();
    if (threadIdx.x == 0) {
        float t = sm[0];
        const int nw = blockDim.x >> 6;
        for (int w = 1; w < nw; ++w) t = fmaxf(t, sm[w]);
        maxn[b] = sqrtf(t);
    }
}

__global__ void scatter_kernel(const float* __restrict__ coords,
                               const float* __restrict__ features,
                               const float* __restrict__ mean,
                               const float* __restrict__ maxn,
                               float* __restrict__ out,
                               float* __restrict__ nc_out,
                               float* __restrict__ counts) {
    const int idx = blockIdx.x * blockDim.x + threadIdx.x;
    if (idx >= B_ * N_) return;
    const int b = idx >> 16;
    const int n = idx & (N_ - 1);
    const float* pc = coords + (size_t)b * 3 * N_;
    const float denom = 2.0f * maxn[b];
    int flat = 0;
    #pragma unroll
    for (int a = 0; a < 3; ++a) {
        float v = (pc[(size_t)a * N_ + n] - mean[b * 3 + a]) / denom + 0.5f;
        v = v * (float)Rr;
        v = fminf(fmaxf(v, 0.0f), (float)(Rr - 1));
        nc_out[(size_t)b * 3 * N_ + (size_t)a * N_ + n] = v;
        flat = flat * Rr + (int)rintf(v);
    }
    atomicAdd(&counts[b * R3 + flat], 1.0f);
    const float* pf = features + (size_t)b * C_ * N_ + n;
    float* po = out + (size_t)b * C_ * R3 + flat;
    #pragma unroll 4
    for (int c = 0; c < C_; ++c) atomicAdd(po + (size_t)c * R3, pf[(size_t)c * N_]);
}

__global__ void finalize_kernel(float* __restrict__ out,
                                const float* __restrict__ counts) {
    const int idx = blockIdx.x * blockDim.x + threadIdx.x;
    if (idx >= B_ * C_ * R3) return;
    const int b = idx / (C_ * R3);
    const int v = idx & (R3 - 1);
    out[idx] = out[idx] / fmaxf(counts[b * R3 + v], 1.0f);
}

extern "C" void kernel_launch(void* const* d_in, const int* in_sizes, int n_in,
                              void* d_out, int out_size, void* d_ws, size_t ws_size,
                              hipStream_t stream) {
    const float* features = (const float*)d_in[0];
    const float* coords   = (const float*)d_in[1];

    float* out    = (float*)d_out;
    float* nc_out = out + (size_t)B_ * C_ * R3;

    const size_t accB   = (size_t)B_ * R3 * C_ * sizeof(float);
    const size_t cntB   = (size_t)B_ * R3 * sizeof(int);
    const size_t curB   = cntB;
    const size_t flatB  = (size_t)B_ * N_ * sizeof(int);
    const size_t clistB = (size_t)B_ * R3 * sizeof(int4);
    const size_t smallB = 16384;
    const size_t ftsB   = (size_t)B_ * N_ * C_;

    const size_t need = accB + cntB + curB + flatB + clistB + smallB + ftsB;
    const int pts = B_ * N_;

    if (ws_size >= need) {
        char* w = (char*)d_ws;
        float* acc    = (float*)w;                 w += accB;
        int*   counts = (int*)w;                   w += cntB;
        int*   cursor = (int*)w;                   w += curB;
        int*   flat   = (int*)w;                   w += flatB;
        int4*  clist  = (int4*)w;                  w += clistB;
        int*   n_occ  = (int*)w;
        float* pmean  = (float*)(w + 16);
        float* pmax   = pmean + B_ * 3 * PBLK;
        w += smallB;
        unsigned char* ftS = (unsigned char*)w;

        pmean_zero_kernel<<<B_ * 3 * PBLK + 256, 256, 0, stream>>>(
            coords, pmean, (int4*)counts, n_occ);
        partial_max_kernel<<<B_ * PBLKM, 256, 0, stream>>>(coords, pmean, pmax);
        voxelize_kernel<<<pts / 256, 256, 0, stream>>>(
            coords, pmean, pmax, nc_out, flat, counts);
        scan_compact_kernel<<<B_, 1024, 0, stream>>>(counts, cursor, clist, n_occ);
        sorted_transpose_ids_kernel<<<B_ * (N_ / 64), 256, 0, stream>>>(
            features, flat, cursor, ftS);
        voxel_sum_compact_kernel<<<2048, 256, 0, stream>>>(ftS, clist, n_occ, acc);
        transpose_finalize_kernel<<<B_ * (R3 / 64), 256, 0, stream>>>(acc, counts, out);
    } else {
        float* counts = (float*)d_ws;
        float* mean   = counts + (size_t)B_ * R3;
        float* maxn   = mean + B_ * 3;

        hipMemsetAsync(d_out, 0, (size_t)B_ * C_ * R3 * sizeof(float), stream);
        hipMemsetAsync(d_ws, 0, ((size_t)B_ * R3 + B_ * 3 + B_) * sizeof(float), stream);

        mean_kernel<<<B_ * 3, 256, 0, stream>>>(coords, mean);
        maxnorm_kernel<<<B_, 1024, 0, stream>>>(coords, mean, maxn);
        scatter_kernel<<<(pts + 255) / 256, 256, 0, stream>>>(
            coords, features, mean, maxn, out, nc_out, counts);
        finalize_kernel<<<(B_ * C_ * R3 + 255) / 256, 256, 0, stream>>>(out, counts);
    }
}